// Round 2
// baseline (1392.438 us; speedup 1.0000x reference)
//
#include <hip/hip_runtime.h>
#include <math.h>

#define NPAIR 80      // B*QPV = 16*5
#define SEQV  2048
#define SEQQ  32
#define VDIM  768
#define QDIM  768
#define HID   512
#define HID2  1024
#define OUTC  5
#define NCHUNK 16
#define CHUNK  128    // SEQV / NCHUNK

// ---------------------------------------------------------------------------
// Kernel A: per-pair effective score vector + question projection.
//   qvec = Wqp @ ques[:,0,:] + bqp            [512]
//   qq   = Wq  @ qvec                          [1024]
//   wk   = Wk^T @ qq                           [512]
//   weff = (Wvp^T @ wk) * scale               [768]   (scale = 1/sqrt(1024))
//   sbias= (bvp . wk)  * scale                scalar
// ---------------------------------------------------------------------------
__global__ __launch_bounds__(1024) void precompute_kernel(
    const float* __restrict__ ques, const float* __restrict__ Wqp,
    const float* __restrict__ bqp,  const float* __restrict__ Wq,
    const float* __restrict__ Wk,   const float* __restrict__ Wvp,
    const float* __restrict__ bvp,
    float* __restrict__ qvec_out, float* __restrict__ weff_out,
    float* __restrict__ sbias_out)
{
    __shared__ float s_q[QDIM];     // ques row, later reused as scratch
    __shared__ float s_qvec[HID];
    __shared__ float s_qq[HID2];
    __shared__ float s_wk[HID];

    const int p    = blockIdx.x;
    const int t    = threadIdx.x;
    const int wave = t >> 6;
    const int lane = t & 63;
    const float scale = 0.03125f;   // 1/sqrt(1024)

    // load question row (seq position 0)
    const float* qrow = ques + (size_t)p * SEQQ * QDIM;
    for (int i = t; i < QDIM; i += 1024) s_q[i] = qrow[i];
    __syncthreads();

    // qvec: 512 rows x dot768 (wave-per-row, float4)
    for (int row = wave; row < HID; row += 16) {
        const float4* w4 = (const float4*)(Wqp + (size_t)row * QDIM);
        const float4* q4 = (const float4*)s_q;
        float acc = 0.f;
        for (int i = lane; i < QDIM / 4; i += 64) {
            float4 w = w4[i], q = q4[i];
            acc += w.x * q.x + w.y * q.y + w.z * q.z + w.w * q.w;
        }
        for (int off = 32; off; off >>= 1) acc += __shfl_xor(acc, off);
        if (lane == 0) s_qvec[row] = acc + bqp[row];
    }
    __syncthreads();

    for (int i = t; i < HID; i += 1024) qvec_out[p * HID + i] = s_qvec[i];

    // qq: 1024 rows x dot512
    for (int row = wave; row < HID2; row += 16) {
        const float4* w4 = (const float4*)(Wq + (size_t)row * HID);
        const float4* q4 = (const float4*)s_qvec;
        float acc = 0.f;
        for (int i = lane; i < HID / 4; i += 64) {
            float4 w = w4[i], q = q4[i];
            acc += w.x * q.x + w.y * q.y + w.z * q.z + w.w * q.w;
        }
        for (int off = 32; off; off >>= 1) acc += __shfl_xor(acc, off);
        if (lane == 0) s_qq[row] = acc;
    }
    __syncthreads();

    // wk[h] = sum_kk Wk[kk,h] * qq[kk]  (column reduction, coalesced over h)
    {
        const int h    = t & (HID - 1);
        const int half = t >> 9;          // 0 or 1, splits kk range
        const int kk0  = half * (HID2 / 2);
        float a0 = 0.f, a1 = 0.f;
        for (int kk = kk0; kk < kk0 + HID2 / 2; kk += 2) {
            a0 += Wk[(size_t)kk * HID + h] * s_qq[kk];
            a1 += Wk[(size_t)(kk + 1) * HID + h] * s_qq[kk + 1];
        }
        if (half == 1) s_q[h] = a0 + a1;   // s_q reused as scratch
        __syncthreads();
        if (half == 0) s_wk[h] = a0 + a1 + s_q[h];
    }
    __syncthreads();

    // weff[d] = scale * sum_h Wvp[h,d] * wk[h]  (coalesced over d)
    if (t < VDIM) {
        float a0 = 0.f, a1 = 0.f;
        for (int h = 0; h < HID; h += 2) {
            a0 += Wvp[(size_t)h * VDIM + t] * s_wk[h];
            a1 += Wvp[(size_t)(h + 1) * VDIM + t] * s_wk[h + 1];
        }
        weff_out[p * VDIM + t] = (a0 + a1) * scale;
    }
    // sbias (wave 15, disjoint from weff threads)
    if (wave == 15) {
        float acc = 0.f;
        for (int h = lane; h < HID; h += 64) acc += bvp[h] * s_wk[h];
        for (int off = 32; off; off >>= 1) acc += __shfl_xor(acc, off);
        if (lane == 0) sbias_out[p] = acc * scale;
    }
}

// ---------------------------------------------------------------------------
// Kernel B: fused score + online-softmax + weighted pooling of raw video rows.
// One block = one 128-row chunk of one (b,q) pair. One pass over video_enc.
// Grid = 80*16 = 1280 blocks = 5/CU -> fully resident, no tail wave.
// ---------------------------------------------------------------------------
__global__ __launch_bounds__(256) void flash_kernel(
    const float* __restrict__ video, const float* __restrict__ weff,
    const float* __restrict__ sbias,
    float* __restrict__ m_out, float* __restrict__ l_out,
    float* __restrict__ acc_out)
{
    const int blk  = blockIdx.x;
    const int p    = blk / NCHUNK;
    const int c    = blk % NCHUNK;
    const int wave = threadIdx.x >> 6;
    const int lane = threadIdx.x & 63;

    const float4* w4 = (const float4*)(weff + (size_t)p * VDIM);
    const float4 wv0 = w4[lane], wv1 = w4[lane + 64], wv2 = w4[lane + 128];
    const float sb = sbias[p];   // already includes 1/sqrt(1024)

    const float* base = video + ((size_t)p * SEQV + (size_t)c * CHUNK) * VDIM;

    float m = -1e30f, l = 0.f;
    float4 a0 = {0, 0, 0, 0}, a1 = {0, 0, 0, 0}, a2 = {0, 0, 0, 0};

    // each wave handles CHUNK/4 = 32 consecutive rows; double-buffer prefetch
    const int R = CHUNK / 4;
    const float* rowp = base + (size_t)(wave * R) * VDIM;
    float4 v0 = ((const float4*)rowp)[lane];
    float4 v1 = ((const float4*)rowp)[lane + 64];
    float4 v2 = ((const float4*)rowp)[lane + 128];
    for (int r = 0; r < R; ++r) {
        // issue next row's loads before the serial reduce chain
        const float* nxtp = rowp + (r + 1 < R ? VDIM : 0);
        const float4 n0 = ((const float4*)nxtp)[lane];
        const float4 n1 = ((const float4*)nxtp)[lane + 64];
        const float4 n2 = ((const float4*)nxtp)[lane + 128];

        float d = v0.x * wv0.x + v0.y * wv0.y + v0.z * wv0.z + v0.w * wv0.w
                + v1.x * wv1.x + v1.y * wv1.y + v1.z * wv1.z + v1.w * wv1.w
                + v2.x * wv2.x + v2.y * wv2.y + v2.z * wv2.z + v2.w * wv2.w;
        for (int off = 32; off; off >>= 1) d += __shfl_xor(d, off);
        const float score = d + sb;
        if (score > m) {                       // wave-uniform branch
            const float corr = __expf(m - score);
            m = score;
            l *= corr;
            a0.x *= corr; a0.y *= corr; a0.z *= corr; a0.w *= corr;
            a1.x *= corr; a1.y *= corr; a1.z *= corr; a1.w *= corr;
            a2.x *= corr; a2.y *= corr; a2.z *= corr; a2.w *= corr;
        }
        const float w = __expf(score - m);
        l += w;
        a0.x += w * v0.x; a0.y += w * v0.y; a0.z += w * v0.z; a0.w += w * v0.w;
        a1.x += w * v1.x; a1.y += w * v1.y; a1.z += w * v1.z; a1.w += w * v1.w;
        a2.x += w * v2.x; a2.y += w * v2.y; a2.z += w * v2.z; a2.w += w * v2.w;

        v0 = n0; v1 = n1; v2 = n2;
        rowp = nxtp;
    }

    // combine the 4 waves of this block
    __shared__ float s_m[4], s_l[4];
    __shared__ float s_acc[4][VDIM];
    if (lane == 0) { s_m[wave] = m; s_l[wave] = l; }
    float4* sa = (float4*)s_acc[wave];
    sa[lane] = a0; sa[lane + 64] = a1; sa[lane + 128] = a2;
    __syncthreads();

    const float M = fmaxf(fmaxf(s_m[0], s_m[1]), fmaxf(s_m[2], s_m[3]));
    const float c0 = __expf(s_m[0] - M), c1 = __expf(s_m[1] - M);
    const float c2 = __expf(s_m[2] - M), c3 = __expf(s_m[3] - M);
    const float L = s_l[0] * c0 + s_l[1] * c1 + s_l[2] * c2 + s_l[3] * c3;

    const int idx = p * NCHUNK + c;
    if (threadIdx.x == 0) { m_out[idx] = M; l_out[idx] = L; }
    float* ao = acc_out + (size_t)idx * VDIM;
    for (int d = threadIdx.x; d < VDIM; d += 256)
        ao[d] = s_acc[0][d] * c0 + s_acc[1][d] * c1 + s_acc[2][d] * c2 + s_acc[3][d] * c3;
}

// ---------------------------------------------------------------------------
// Kernel C: combine chunks -> vbar -> project -> classifier -> softmax.
// ---------------------------------------------------------------------------
__global__ __launch_bounds__(256) void head_kernel(
    const float* __restrict__ m_in, const float* __restrict__ l_in,
    const float* __restrict__ acc_in, const float* __restrict__ qvec_in,
    const float* __restrict__ Wvp, const float* __restrict__ bvp,
    const float* __restrict__ Wv,
    const float* __restrict__ W1, const float* __restrict__ b1,
    const float* __restrict__ W2, const float* __restrict__ b2,
    const float* __restrict__ omask, float* __restrict__ out)
{
    __shared__ float s_vbar[VDIM];
    __shared__ float s_x[HID2];     // pooled(512) ++ qvec(512)
    __shared__ float s_h1[HID];     // vh, later relu hidden
    __shared__ float s_coef[NCHUNK];
    __shared__ float s_out[OUTC];

    const int p    = blockIdx.x;
    const int t    = threadIdx.x;
    const int wave = t >> 6;
    const int lane = t & 63;

    // softmax-combine coefficients across chunks
    if (wave == 0) {
        const float mv = (lane < NCHUNK) ? m_in[p * NCHUNK + lane] : -1e30f;
        float M = mv;
        for (int off = 32; off; off >>= 1) M = fmaxf(M, __shfl_xor(M, off));
        const float lv = (lane < NCHUNK) ? l_in[p * NCHUNK + lane] : 0.f;
        const float ce = (lane < NCHUNK) ? __expf(mv - M) : 0.f;
        float L = lv * ce;
        for (int off = 32; off; off >>= 1) L += __shfl_xor(L, off);
        if (lane < NCHUNK) s_coef[lane] = ce / L;
    }
    __syncthreads();

    // vbar[d] = sum_c coef[c] * acc[c][d]   (attention-weighted mean video row)
    for (int d = t; d < VDIM; d += 256) {
        float acc = 0.f;
        for (int c = 0; c < NCHUNK; ++c)
            acc += s_coef[c] * acc_in[((size_t)(p * NCHUNK + c)) * VDIM + d];
        s_vbar[d] = acc;
    }
    __syncthreads();

    // vh = Wvp @ vbar + bvp   -> s_h1
    for (int row = wave; row < HID; row += 4) {
        const float4* w4 = (const float4*)(Wvp + (size_t)row * VDIM);
        const float4* v4 = (const float4*)s_vbar;
        float acc = 0.f;
        for (int i = lane; i < VDIM / 4; i += 64) {
            float4 w = w4[i], v = v4[i];
            acc += w.x * v.x + w.y * v.y + w.z * v.z + w.w * v.w;
        }
        for (int off = 32; off; off >>= 1) acc += __shfl_xor(acc, off);
        if (lane == 0) s_h1[row] = acc + bvp[row];
    }
    __syncthreads();

    // pooled = Wv @ vh -> s_x[0:512]
    for (int row = wave; row < HID; row += 4) {
        const float4* w4 = (const float4*)(Wv + (size_t)row * HID);
        const float4* v4 = (const float4*)s_h1;
        float acc = 0.f;
        for (int i = lane; i < HID / 4; i += 64) {
            float4 w = w4[i], v = v4[i];
            acc += w.x * v.x + w.y * v.y + w.z * v.z + w.w * v.w;
        }
        for (int off = 32; off; off >>= 1) acc += __shfl_xor(acc, off);
        if (lane == 0) s_x[row] = acc;
    }
    // x[512:1024] = qvec
    for (int i = t; i < HID; i += 256) s_x[HID + i] = qvec_in[p * HID + i];
    __syncthreads();

    // h1 = relu(W1 @ x + b1)  (overwrites s_h1 — vh consumed above)
    for (int row = wave; row < HID; row += 4) {
        const float4* w4 = (const float4*)(W1 + (size_t)row * HID2);
        const float4* v4 = (const float4*)s_x;
        float acc = 0.f;
        for (int i = lane; i < HID2 / 4; i += 64) {
            float4 w = w4[i], v = v4[i];
            acc += w.x * v.x + w.y * v.y + w.z * v.z + w.w * v.w;
        }
        for (int off = 32; off; off >>= 1) acc += __shfl_xor(acc, off);
        if (lane == 0) s_h1[row] = fmaxf(acc + b1[row], 0.f);
    }
    __syncthreads();

    // out = softmax(W2 @ h1 + b2 + output_mask)
    if (wave == 0) {
        for (int o = 0; o < OUTC; ++o) {
            const float4* w4 = (const float4*)(W2 + (size_t)o * HID);
            const float4* v4 = (const float4*)s_h1;
            float acc = 0.f;
            for (int i = lane; i < HID / 4; i += 64) {
                float4 w = w4[i], v = v4[i];
                acc += w.x * v.x + w.y * v.y + w.z * v.z + w.w * v.w;
            }
            for (int off = 32; off; off >>= 1) acc += __shfl_xor(acc, off);
            if (lane == 0) s_out[o] = acc + b2[o] + omask[p * OUTC + o];
        }
        if (lane == 0) {
            float M = s_out[0];
            for (int o = 1; o < OUTC; ++o) M = fmaxf(M, s_out[o]);
            float e[OUTC], S = 0.f;
            for (int o = 0; o < OUTC; ++o) { e[o] = __expf(s_out[o] - M); S += e[o]; }
            const float inv = 1.f / S;
            for (int o = 0; o < OUTC; ++o) out[p * OUTC + o] = e[o] * inv;
        }
    }
}

// ---------------------------------------------------------------------------
extern "C" void kernel_launch(void* const* d_in, const int* in_sizes, int n_in,
                              void* d_out, int out_size, void* d_ws, size_t ws_size,
                              hipStream_t stream)
{
    const float* video = (const float*)d_in[0];
    const float* ques  = (const float*)d_in[1];
    // d_in[2] = ques_mask (all-ones; unused by the reference math)
    const float* omask = (const float*)d_in[3];
    const float* Wvp   = (const float*)d_in[4];
    const float* bvp   = (const float*)d_in[5];
    const float* Wqp   = (const float*)d_in[6];
    const float* bqp   = (const float*)d_in[7];
    const float* Wk    = (const float*)d_in[8];
    const float* Wv    = (const float*)d_in[9];
    const float* Wq    = (const float*)d_in[10];
    const float* W1    = (const float*)d_in[11];
    const float* b1    = (const float*)d_in[12];
    const float* W2    = (const float*)d_in[13];
    const float* b2    = (const float*)d_in[14];
    float* out = (float*)d_out;

    float* ws     = (float*)d_ws;
    float* qvec   = ws;                        // 80*512
    float* weff   = qvec + NPAIR * HID;        // 80*768
    float* sbias  = weff + NPAIR * VDIM;       // 80
    float* m_ws   = sbias + NPAIR;             // 80*16
    float* l_ws   = m_ws + NPAIR * NCHUNK;     // 80*16
    float* acc_ws = l_ws + NPAIR * NCHUNK;     // 80*16*768  (~4.3 MB total)

    hipLaunchKernelGGL(precompute_kernel, dim3(NPAIR), dim3(1024), 0, stream,
                       ques, Wqp, bqp, Wq, Wk, Wvp, bvp, qvec, weff, sbias);
    hipLaunchKernelGGL(flash_kernel, dim3(NPAIR * NCHUNK), dim3(256), 0, stream,
                       video, weff, sbias, m_ws, l_ws, acc_ws);
    hipLaunchKernelGGL(head_kernel, dim3(NPAIR), dim3(256), 0, stream,
                       m_ws, l_ws, acc_ws, qvec, Wvp, bvp, Wv, W1, b1, W2, b2,
                       omask, out);
}

// Round 3
// 786.792 us; speedup vs baseline: 1.7698x; 1.7698x over previous
//
#include <hip/hip_runtime.h>
#include <math.h>

#define NPAIR 80      // B*QPV = 16*5
#define SEQV  2048
#define SEQQ  32
#define VDIM  768
#define QDIM  768
#define HID   512
#define HID2  1024
#define OUTC  5
#define NCHUNK 16
#define CHUNK  128    // SEQV / NCHUNK
#define KKCH  4       // kk-chunks for the Wk^T partial reduction
#define KKLEN (HID2 / KKCH)   // 256

// ---------------------------------------------------------------------------
// Generic wave-per-output batched matvec:
//   y[p*ystride + yoff + row] = act( W[row,:K] . x[p*xstride : +K] + b[row] )
// Grid = NPAIR*ROWS/4 blocks of 256 (4 waves). Massive TLP; W rows L2-hot.
// ---------------------------------------------------------------------------
template<int K4, int ROWS, bool RELU>
__global__ __launch_bounds__(256) void matvec_kernel(
    const float* __restrict__ W, const float* __restrict__ x,
    const float* __restrict__ bias, float* __restrict__ y,
    int xstride, int ystride, int yoff)
{
    const int wave = threadIdx.x >> 6, lane = threadIdx.x & 63;
    const int o = blockIdx.x * 4 + wave;
    const int p = o / ROWS, row = o % ROWS;
    const float4* w4 = (const float4*)(W + (size_t)row * (K4 * 4));
    const float4* x4 = (const float4*)(x + (size_t)p * xstride);
    float acc = 0.f;
#pragma unroll
    for (int j = 0; j < K4 / 64; ++j) {
        float4 w = w4[lane + 64 * j], v = x4[lane + 64 * j];
        acc += w.x * v.x + w.y * v.y + w.z * v.z + w.w * v.w;
    }
#pragma unroll
    for (int off = 32; off; off >>= 1) acc += __shfl_xor(acc, off);
    if (lane == 0) {
        float r = acc + (bias ? bias[row] : 0.f);
        if (RELU) r = fmaxf(r, 0.f);
        y[(size_t)p * ystride + yoff + row] = r;
    }
}

// ---------------------------------------------------------------------------
// wkpart[p][kc][h] = sum_{kk in chunk kc} Wk[kk][h] * qq[p][kk]
// thread-per-h (coalesced over h), qq chunk broadcast from LDS.
// Grid = NPAIR * 2(hc) * KKCH = 640 blocks of 256.
// ---------------------------------------------------------------------------
__global__ __launch_bounds__(256) void wkpart_kernel(
    const float* __restrict__ Wk, const float* __restrict__ qq,
    float* __restrict__ wkpart)
{
    const int b   = blockIdx.x;
    const int p   = b / (2 * KKCH);
    const int rem = b % (2 * KKCH);
    const int hc  = rem / KKCH, kc = rem % KKCH;
    __shared__ float s_qq[KKLEN];
    const int t = threadIdx.x;
    s_qq[t] = qq[(size_t)p * HID2 + kc * KKLEN + t];   // KKLEN == 256
    __syncthreads();
    const int h = hc * 256 + t;
    const float* wp = Wk + (size_t)(kc * KKLEN) * HID + h;
    float acc = 0.f;
#pragma unroll 8
    for (int kk = 0; kk < KKLEN; ++kk)
        acc += wp[(size_t)kk * HID] * s_qq[kk];
    wkpart[((size_t)p * KKCH + kc) * HID + h] = acc;
}

// ---------------------------------------------------------------------------
// weff[p][d] = scale * sum_h Wvp[h][d] * wk[p][h]   (wk = sum of partials)
// sbias[p]   = scale * bvp . wk[p]                  (block dc==0)
// Grid = NPAIR*3 blocks of 256 (thread-per-d, coalesced).
// ---------------------------------------------------------------------------
__global__ __launch_bounds__(256) void weff_kernel(
    const float* __restrict__ wkpart, const float* __restrict__ Wvp,
    const float* __restrict__ bvp,
    float* __restrict__ weff, float* __restrict__ sbias)
{
    const int p = blockIdx.x / 3, dc = blockIdx.x % 3;
    __shared__ float s_wk[HID];
    const int t = threadIdx.x;
    const float* base = wkpart + (size_t)p * KKCH * HID;
    for (int i = t; i < HID; i += 256)
        s_wk[i] = base[i] + base[HID + i] + base[2 * HID + i] + base[3 * HID + i];
    __syncthreads();
    const float scale = 0.03125f;   // 1/sqrt(1024)
    if (dc == 0 && t < 64) {
        float a = 0.f;
        for (int h = t; h < HID; h += 64) a += bvp[h] * s_wk[h];
#pragma unroll
        for (int off = 32; off; off >>= 1) a += __shfl_xor(a, off);
        if (t == 0) sbias[p] = a * scale;
    }
    const int d = dc * 256 + t;
    const float* wp = Wvp + d;
    float acc = 0.f;
#pragma unroll 8
    for (int h = 0; h < HID; ++h)
        acc += wp[(size_t)h * VDIM] * s_wk[h];
    weff[(size_t)p * VDIM + d] = acc * scale;
}

// ---------------------------------------------------------------------------
// Kernel B: fused score + online-softmax + weighted pooling of raw video rows.
// One block = one 128-row chunk of one (b,q) pair. One pass over video_enc.
// Grid = 80*16 = 1280 blocks = 5/CU -> fully resident, no tail wave.
// ---------------------------------------------------------------------------
__global__ __launch_bounds__(256) void flash_kernel(
    const float* __restrict__ video, const float* __restrict__ weff,
    const float* __restrict__ sbias,
    float* __restrict__ m_out, float* __restrict__ l_out,
    float* __restrict__ acc_out)
{
    const int blk  = blockIdx.x;
    const int p    = blk / NCHUNK;
    const int c    = blk % NCHUNK;
    const int wave = threadIdx.x >> 6;
    const int lane = threadIdx.x & 63;

    const float4* w4 = (const float4*)(weff + (size_t)p * VDIM);
    const float4 wv0 = w4[lane], wv1 = w4[lane + 64], wv2 = w4[lane + 128];
    const float sb = sbias[p];   // already includes 1/sqrt(1024)

    const float* base = video + ((size_t)p * SEQV + (size_t)c * CHUNK) * VDIM;

    float m = -1e30f, l = 0.f;
    float4 a0 = {0, 0, 0, 0}, a1 = {0, 0, 0, 0}, a2 = {0, 0, 0, 0};

    const int R = CHUNK / 4;
    const float* rowp = base + (size_t)(wave * R) * VDIM;
    float4 v0 = ((const float4*)rowp)[lane];
    float4 v1 = ((const float4*)rowp)[lane + 64];
    float4 v2 = ((const float4*)rowp)[lane + 128];
    for (int r = 0; r < R; ++r) {
        const float* nxtp = rowp + (r + 1 < R ? VDIM : 0);
        const float4 n0 = ((const float4*)nxtp)[lane];
        const float4 n1 = ((const float4*)nxtp)[lane + 64];
        const float4 n2 = ((const float4*)nxtp)[lane + 128];

        float d = v0.x * wv0.x + v0.y * wv0.y + v0.z * wv0.z + v0.w * wv0.w
                + v1.x * wv1.x + v1.y * wv1.y + v1.z * wv1.z + v1.w * wv1.w
                + v2.x * wv2.x + v2.y * wv2.y + v2.z * wv2.z + v2.w * wv2.w;
        for (int off = 32; off; off >>= 1) d += __shfl_xor(d, off);
        const float score = d + sb;
        if (score > m) {                       // wave-uniform branch
            const float corr = __expf(m - score);
            m = score;
            l *= corr;
            a0.x *= corr; a0.y *= corr; a0.z *= corr; a0.w *= corr;
            a1.x *= corr; a1.y *= corr; a1.z *= corr; a1.w *= corr;
            a2.x *= corr; a2.y *= corr; a2.z *= corr; a2.w *= corr;
        }
        const float w = __expf(score - m);
        l += w;
        a0.x += w * v0.x; a0.y += w * v0.y; a0.z += w * v0.z; a0.w += w * v0.w;
        a1.x += w * v1.x; a1.y += w * v1.y; a1.z += w * v1.z; a1.w += w * v1.w;
        a2.x += w * v2.x; a2.y += w * v2.y; a2.z += w * v2.z; a2.w += w * v2.w;

        v0 = n0; v1 = n1; v2 = n2;
        rowp = nxtp;
    }

    __shared__ float s_m[4], s_l[4];
    __shared__ float s_acc[4][VDIM];
    if (lane == 0) { s_m[wave] = m; s_l[wave] = l; }
    float4* sa = (float4*)s_acc[wave];
    sa[lane] = a0; sa[lane + 64] = a1; sa[lane + 128] = a2;
    __syncthreads();

    const float M = fmaxf(fmaxf(s_m[0], s_m[1]), fmaxf(s_m[2], s_m[3]));
    const float c0 = __expf(s_m[0] - M), c1 = __expf(s_m[1] - M);
    const float c2 = __expf(s_m[2] - M), c3 = __expf(s_m[3] - M);
    const float L = s_l[0] * c0 + s_l[1] * c1 + s_l[2] * c2 + s_l[3] * c3;

    const int idx = p * NCHUNK + c;
    if (threadIdx.x == 0) { m_out[idx] = M; l_out[idx] = L; }
    float* ao = acc_out + (size_t)idx * VDIM;
    for (int d = threadIdx.x; d < VDIM; d += 256)
        ao[d] = s_acc[0][d] * c0 + s_acc[1][d] * c1 + s_acc[2][d] * c2 + s_acc[3][d] * c3;
}

// ---------------------------------------------------------------------------
// coef+vbar: softmax-combine chunk results, vbar[p][d] = sum_c coef*acc[c][d]
// Grid = NPAIR*3 blocks of 256.
// ---------------------------------------------------------------------------
__global__ __launch_bounds__(256) void coef_vbar_kernel(
    const float* __restrict__ m_in, const float* __restrict__ l_in,
    const float* __restrict__ acc_in, float* __restrict__ vbar)
{
    const int p = blockIdx.x / 3, dc = blockIdx.x % 3;
    __shared__ float s_coef[NCHUNK];
    const int t = threadIdx.x;
    if (t < 64) {
        const float mv = (t < NCHUNK) ? m_in[p * NCHUNK + t] : -1e30f;
        float M = mv;
#pragma unroll
        for (int off = 32; off; off >>= 1) M = fmaxf(M, __shfl_xor(M, off));
        const float lv = (t < NCHUNK) ? l_in[p * NCHUNK + t] : 0.f;
        const float ce = (t < NCHUNK) ? __expf(mv - M) : 0.f;
        float L = lv * ce;
#pragma unroll
        for (int off = 32; off; off >>= 1) L += __shfl_xor(L, off);
        if (t < NCHUNK) s_coef[t] = ce / L;
    }
    __syncthreads();
    const int d = dc * 256 + t;
    float a = 0.f;
#pragma unroll
    for (int c = 0; c < NCHUNK; ++c)
        a += s_coef[c] * acc_in[((size_t)p * NCHUNK + c) * VDIM + d];
    vbar[(size_t)p * VDIM + d] = a;
}

// ---------------------------------------------------------------------------
// logits + 5-way softmax. Grid = NPAIR blocks of 64 (one wave each).
// ---------------------------------------------------------------------------
__global__ __launch_bounds__(64) void logits_kernel(
    const float* __restrict__ h1, const float* __restrict__ W2,
    const float* __restrict__ b2, const float* __restrict__ omask,
    float* __restrict__ out)
{
    const int p = blockIdx.x, lane = threadIdx.x;
    const float4* x4 = (const float4*)(h1 + (size_t)p * HID);
    float logit[OUTC];
#pragma unroll
    for (int o = 0; o < OUTC; ++o) {
        const float4* w4 = (const float4*)(W2 + (size_t)o * HID);
        float acc = 0.f;
#pragma unroll
        for (int j = 0; j < 2; ++j) {
            float4 w = w4[lane + 64 * j], v = x4[lane + 64 * j];
            acc += w.x * v.x + w.y * v.y + w.z * v.z + w.w * v.w;
        }
#pragma unroll
        for (int off = 32; off; off >>= 1) acc += __shfl_xor(acc, off);
        logit[o] = acc;   // valid in lane 0
    }
    if (lane == 0) {
        float M = -1e30f;
#pragma unroll
        for (int o = 0; o < OUTC; ++o) {
            logit[o] += b2[o] + omask[p * OUTC + o];
            M = fmaxf(M, logit[o]);
        }
        float e[OUTC], S = 0.f;
#pragma unroll
        for (int o = 0; o < OUTC; ++o) { e[o] = __expf(logit[o] - M); S += e[o]; }
        const float inv = 1.f / S;
#pragma unroll
        for (int o = 0; o < OUTC; ++o) out[p * OUTC + o] = e[o] * inv;
    }
}

// ---------------------------------------------------------------------------
extern "C" void kernel_launch(void* const* d_in, const int* in_sizes, int n_in,
                              void* d_out, int out_size, void* d_ws, size_t ws_size,
                              hipStream_t stream)
{
    const float* video = (const float*)d_in[0];
    const float* ques  = (const float*)d_in[1];
    // d_in[2] = ques_mask (all-ones; unused by the reference math)
    const float* omask = (const float*)d_in[3];
    const float* Wvp   = (const float*)d_in[4];
    const float* bvp   = (const float*)d_in[5];
    const float* Wqp   = (const float*)d_in[6];
    const float* bqp   = (const float*)d_in[7];
    const float* Wk    = (const float*)d_in[8];
    const float* Wv    = (const float*)d_in[9];
    const float* Wq    = (const float*)d_in[10];
    const float* W1    = (const float*)d_in[11];
    const float* b1    = (const float*)d_in[12];
    const float* W2    = (const float*)d_in[13];
    const float* b2    = (const float*)d_in[14];
    float* out = (float*)d_out;

    float* ws     = (float*)d_ws;
    float* xbuf   = ws;                         // 80*1024  (pooled ++ qvec)
    float* qq     = xbuf   + NPAIR * HID2;      // 80*1024
    float* wkpart = qq     + NPAIR * HID2;      // 80*4*512
    float* weff   = wkpart + NPAIR * KKCH * HID;// 80*768
    float* sbias  = weff   + NPAIR * VDIM;      // 80
    float* m_ws   = sbias  + NPAIR;             // 80*16
    float* l_ws   = m_ws   + NPAIR * NCHUNK;    // 80*16
    float* acc_ws = l_ws   + NPAIR * NCHUNK;    // 80*16*768
    float* vbar   = acc_ws + NPAIR * NCHUNK * VDIM; // 80*768
    float* vh     = vbar   + NPAIR * VDIM;      // 80*512
    float* h1     = vh     + NPAIR * HID;       // 80*512   (~5.8 MB total)

    // ---- precompute chain (wide-parallel stages) ----
    // qvec -> xbuf[:,512:1024]
    hipLaunchKernelGGL((matvec_kernel<QDIM / 4, HID, false>),
                       dim3(NPAIR * HID / 4), dim3(256), 0, stream,
                       Wqp, ques, bqp, xbuf, SEQQ * QDIM, HID2, HID);
    // qq = Wq @ qvec
    hipLaunchKernelGGL((matvec_kernel<HID / 4, HID2, false>),
                       dim3(NPAIR * HID2 / 4), dim3(256), 0, stream,
                       Wq, xbuf + HID, (const float*)nullptr, qq, HID2, HID2, 0);
    // wk partials = Wk^T @ qq
    hipLaunchKernelGGL(wkpart_kernel, dim3(NPAIR * 2 * KKCH), dim3(256), 0, stream,
                       Wk, qq, wkpart);
    // weff = scale * Wvp^T @ wk ; sbias = scale * bvp.wk
    hipLaunchKernelGGL(weff_kernel, dim3(NPAIR * 3), dim3(256), 0, stream,
                       wkpart, Wvp, bvp, weff, sbias);

    // ---- single pass over video ----
    hipLaunchKernelGGL(flash_kernel, dim3(NPAIR * NCHUNK), dim3(256), 0, stream,
                       video, weff, sbias, m_ws, l_ws, acc_ws);

    // ---- head (wide-parallel stages) ----
    hipLaunchKernelGGL(coef_vbar_kernel, dim3(NPAIR * 3), dim3(256), 0, stream,
                       m_ws, l_ws, acc_ws, vbar);
    // vh = Wvp @ vbar + bvp
    hipLaunchKernelGGL((matvec_kernel<VDIM / 4, HID, false>),
                       dim3(NPAIR * HID / 4), dim3(256), 0, stream,
                       Wvp, vbar, bvp, vh, VDIM, HID, 0);
    // pooled = Wv @ vh -> xbuf[:,0:512]
    hipLaunchKernelGGL((matvec_kernel<HID / 4, HID, false>),
                       dim3(NPAIR * HID / 4), dim3(256), 0, stream,
                       Wv, vh, (const float*)nullptr, xbuf, HID, HID2, 0);
    // h1 = relu(W1 @ [pooled;qvec] + b1)
    hipLaunchKernelGGL((matvec_kernel<HID2 / 4, HID, true>),
                       dim3(NPAIR * HID / 4), dim3(256), 0, stream,
                       W1, xbuf, b1, h1, HID2, HID, 0);
    // logits + softmax
    hipLaunchKernelGGL(logits_kernel, dim3(NPAIR), dim3(64), 0, stream,
                       h1, W2, b2, omask, out);
}